// Round 3
// baseline (344.332 us; speedup 1.0000x reference)
//
#include <hip/hip_runtime.h>
#include <math.h>

#define BATCH  32768
#define D      128
#define K      6400
#define KC     64
#define ROWS_PER_BLOCK 32
#define CHUNK_C 64
#define NCHUNK (K / CHUNK_C)   // 100

typedef _Float16 half8 __attribute__((ext_vector_type(8)));
typedef float    floatx4 __attribute__((ext_vector_type(4)));

typedef __attribute__((address_space(3))) unsigned       lds_uint;
typedef __attribute__((address_space(1))) const unsigned glb_uint;

__device__ __forceinline__ void async_lds16(const void* g, void* l) {
    __builtin_amdgcn_global_load_lds((glb_uint*)g, (lds_uint*)l, 16, 0, 0);
}

// ---- pack centers into split-fp16 hi/lo (chunk-major for global_load_lds)
//      + fused c2[k] = ||c_k||^2 (blocks 0..99) ----
// 16B-chunk index n = ch*1024 + u*64 + cw  holds center (ch*64+cw), k in [u*8,u*8+8).
__global__ __launch_bounds__(256) void pack_kernel(const float* __restrict__ centers,
                                                   _Float16* __restrict__ wh,
                                                   _Float16* __restrict__ wl,
                                                   float* __restrict__ c2) {
    int tid = blockIdx.x * 256 + threadIdx.x;   // 0 .. K*16-1
    int ch = tid >> 10;
    int rr = tid & 1023;
    int u  = rr >> 6;
    int cw = rr & 63;
    int center = ch * CHUNK_C + cw;
    const float* src = centers + (size_t)center * D + u * 8;
    float4 a = *(const float4*)src;
    float4 b = *(const float4*)(src + 4);
    float f[8] = {a.x, a.y, a.z, a.w, b.x, b.y, b.z, b.w};
    half8 h, l;
#pragma unroll
    for (int j = 0; j < 8; ++j) {
        _Float16 hi = (_Float16)f[j];
        h[j] = hi;
        l[j] = (_Float16)(f[j] - (float)hi);
    }
    *(half8*)(wh + (size_t)tid * 8) = h;
    *(half8*)(wl + (size_t)tid * 8) = l;

    // fused c2: blocks 0..99 each cover 64 centers, 4 threads per center
    if (blockIdx.x < K / KC) {
        int c_local = threadIdx.x >> 2, part = threadIdx.x & 3;
        int c = blockIdx.x * 64 + c_local;
        const float4* p = (const float4*)(centers + (size_t)c * D + part * 32);
        float s = 0.f;
#pragma unroll
        for (int i = 0; i < 8; ++i) {
            float4 v = p[i];
            s = fmaf(v.x, v.x, s); s = fmaf(v.y, v.y, s);
            s = fmaf(v.z, v.z, s); s = fmaf(v.w, v.w, s);
        }
        s += __shfl_xor(s, 1, 64);
        s += __shfl_xor(s, 2, 64);
        if (part == 0) c2[c] = s;
    }
}

// ---- main fused kernel ----
// Block: 256 threads = 4 waves, 32 rows. Wave w owns center-quarter q=w (16 of 64
// chunk centers); wave tile = 32 rows x 16 centers (rt=2 keeps B-fragment reuse).
// A (x rows, split-fp16) register-resident; B streamed via global_load_lds, 32 KB
// LDS -> 4 blocks/CU (vs 2 in R2): more independent barrier domains to hide the
// vmcnt(0) drain at each __syncthreads.
// 3-pass split MFMA: acc += Ah*Bh + Ah*Bl + Al*Bh  (score err ~5e-7 rel).
// Best-2 per (row, quarter) -> 8 candidates/row, exact fp32 refine at the end.
__global__ __launch_bounds__(256, 4) void dist_kernel(
    const float* __restrict__ x, const float* __restrict__ centers,
    const _Float16* __restrict__ wh, const _Float16* __restrict__ wl,
    const float* __restrict__ c2g, float* __restrict__ out) {
    __shared__ char lds[32768];   // [hi 16KB][lo 16KB]; aliased for epilogue comms

    const int t    = threadIdx.x;
    const int w    = t >> 6;       // center-quarter
    const int L    = t & 63;
    const int quad = L >> 4;
    const int n16  = L & 15;
    const int gr0  = blockIdx.x * ROWS_PER_BLOCK;

    // ---- preload A fragments (32 rows x 128 k, hi+lo; same for all 4 waves) ----
    half8 Ah[2][4], Al[2][4];
#pragma unroll
    for (int rt = 0; rt < 2; ++rt) {
        int r = gr0 + rt * 16 + n16;
        const float* xr = x + (size_t)r * D + quad * 8;
#pragma unroll
        for (int ks = 0; ks < 4; ++ks) {
            float4 a = *(const float4*)(xr + ks * 32);
            float4 b = *(const float4*)(xr + ks * 32 + 4);
            float f[8] = {a.x, a.y, a.z, a.w, b.x, b.y, b.z, b.w};
            half8 h, l;
#pragma unroll
            for (int j = 0; j < 8; ++j) {
                _Float16 hi = (_Float16)f[j];
                h[j] = hi;
                l[j] = (_Float16)(f[j] - (float)hi);
            }
            Ah[rt][ks] = h;
            Al[rt][ks] = l;
        }
    }

    float b1[8], b2[8];
    int   j1_[8], j2_[8];
#pragma unroll
    for (int k = 0; k < 8; ++k) { b1[k] = 3.4e38f; b2[k] = 3.4e38f; j1_[k] = 0; j2_[k] = 0; }

    for (int ch = 0; ch < NCHUNK; ++ch) {
        __syncthreads();   // previous chunk's LDS reads complete
        const char* gh = (const char*)wh + (size_t)ch * 16384;
        const char* gl = (const char*)wl + (size_t)ch * 16384;
#pragma unroll
        for (int i = 0; i < 4; ++i) {
            int seg = w + i * 4;                       // wave-uniform
            async_lds16(gh + seg * 1024 + L * 16, lds + seg * 1024);
        }
#pragma unroll
        for (int i = 0; i < 4; ++i) {
            int seg = w + i * 4;
            async_lds16(gl + seg * 1024 + L * 16, lds + 16384 + seg * 1024);
        }
        float c2v = c2g[ch * CHUNK_C + w * 16 + n16];  // this thread's center column
        __syncthreads();   // staging complete

        floatx4 acc[2];
        acc[0] = (floatx4){0.f, 0.f, 0.f, 0.f};
        acc[1] = (floatx4){0.f, 0.f, 0.f, 0.f};

        const half8* pb = (const half8*)lds + w * 16 + n16;   // hi base; lo at +1024
#pragma unroll
        for (int ks = 0; ks < 4; ++ks) {
            half8 Bh = pb[(ks * 4 + quad) * 64];
            half8 Bl = pb[1024 + (ks * 4 + quad) * 64];
            acc[0] = __builtin_amdgcn_mfma_f32_16x16x32_f16(Ah[0][ks], Bh, acc[0], 0, 0, 0);
            acc[1] = __builtin_amdgcn_mfma_f32_16x16x32_f16(Ah[1][ks], Bh, acc[1], 0, 0, 0);
            acc[0] = __builtin_amdgcn_mfma_f32_16x16x32_f16(Ah[0][ks], Bl, acc[0], 0, 0, 0);
            acc[1] = __builtin_amdgcn_mfma_f32_16x16x32_f16(Ah[1][ks], Bl, acc[1], 0, 0, 0);
            acc[0] = __builtin_amdgcn_mfma_f32_16x16x32_f16(Al[0][ks], Bh, acc[0], 0, 0, 0);
            acc[1] = __builtin_amdgcn_mfma_f32_16x16x32_f16(Al[1][ks], Bh, acc[1], 0, 0, 0);
        }

        // best-2 tracking; center index is uniform per thread this chunk
        int idx = ch * CHUNK_C + w * 16 + n16;
#pragma unroll
        for (int rt = 0; rt < 2; ++rt)
#pragma unroll
            for (int reg = 0; reg < 4; ++reg) {
                float s = fmaf(-2.f, acc[rt][reg], c2v);
                int k = rt * 4 + reg;
                bool bet1 = s < b1[k];
                bool bet2 = s < b2[k];
                float nb2 = bet1 ? b1[k] : (bet2 ? s : b2[k]);
                int   nj2 = bet1 ? j1_[k] : (bet2 ? idx : j2_[k]);
                b1[k]  = bet1 ? s : b1[k];
                j1_[k] = bet1 ? idx : j1_[k];
                b2[k]  = nb2;
                j2_[k] = nj2;
            }
    }

    __syncthreads();              // LDS free for reuse
    int* candL = (int*)lds;       // [32 rows][8 candidates]

    // merge sorted best-2 pairs across the 16 center-columns of this quarter
#pragma unroll
    for (int k = 0; k < 8; ++k) {
        float v1 = b1[k], v2 = b2[k];
        int   p1 = j1_[k], p2 = j2_[k];
#pragma unroll
        for (int m = 1; m < 16; m <<= 1) {
            float o1 = __shfl_xor(v1, m, 64), o2 = __shfl_xor(v2, m, 64);
            int   q1 = __shfl_xor(p1, m, 64), q2 = __shfl_xor(p2, m, 64);
            bool firstMine = (v1 < o1) || (v1 == o1 && p1 < q1);
            float nv1 = firstMine ? v1 : o1;  int np1 = firstMine ? p1 : q1;
            float cb  = firstMine ? o1 : v1;  int cpi = firstMine ? q1 : p1;  // loser of firsts
            float ob  = firstMine ? v2 : o2;  int obi = firstMine ? p2 : q2;  // winner's own 2nd
            bool secOwn = (ob < cb) || (ob == cb && obi < cpi);
            v1 = nv1; p1 = np1;
            v2 = secOwn ? ob : cb;  p2 = secOwn ? obi : cpi;
        }
        if (n16 == 0) {
            int rloc = (k >> 2) * 16 + quad * 4 + (k & 3);   // rt*16 + quad*4 + reg
            candL[rloc * 8 + w * 2 + 0] = p1;
            candL[rloc * 8 + w * 2 + 1] = p2;
        }
    }
    __syncthreads();

    float* out_q   = out;
    float* out_clu = out + (size_t)BATCH * D;
    float* out_md  = out_clu + BATCH;
    float* out_cls = out_md + BATCH;

    // exact fp32 refine: 8 candidates per row, one thread each (32*8 = 256)
    {
        int r = t >> 3, cpos = t & 7;
        int ix = candL[r * 8 + cpos];
        const float4* xr4 = (const float4*)(x + (size_t)(gr0 + r) * D);
        const float4* cr4 = (const float4*)(centers + (size_t)ix * D);
        float dot = 0.f, x2s = 0.f, c2s = 0.f;
#pragma unroll
        for (int d4 = 0; d4 < 32; ++d4) {
            float4 xv = xr4[d4], cv = cr4[d4];
            dot = fmaf(xv.x, cv.x, dot); dot = fmaf(xv.y, cv.y, dot);
            dot = fmaf(xv.z, cv.z, dot); dot = fmaf(xv.w, cv.w, dot);
            x2s = fmaf(xv.x, xv.x, x2s); x2s = fmaf(xv.y, xv.y, x2s);
            x2s = fmaf(xv.z, xv.z, x2s); x2s = fmaf(xv.w, xv.w, x2s);
            c2s = fmaf(cv.x, cv.x, c2s); c2s = fmaf(cv.y, cv.y, c2s);
            c2s = fmaf(cv.z, cv.z, c2s); c2s = fmaf(cv.w, cv.w, c2s);
        }
        float sq = x2s + c2s - 2.f * dot;
#pragma unroll
        for (int m = 1; m < 8; m <<= 1) {
            float osq = __shfl_xor(sq, m, 64);
            int   oix = __shfl_xor(ix, m, 64);
            if (osq < sq || (osq == sq && oix < ix)) { sq = osq; ix = oix; }
        }
        int* winL = (int*)(lds + 16384);
        if (cpos == 0) {
            out_md[gr0 + r]  = sqrtf(fmaxf(sq, 0.f));
            out_clu[gr0 + r] = (float)(ix & (KC - 1));
            out_cls[gr0 + r] = (float)(ix >> 6);
            winL[r] = ix;
        }
    }
    __syncthreads();

    // quantized = x + (c - x), coalesced
    {
        const int* winL = (const int*)(lds + 16384);
        const float4* cg4 = (const float4*)centers;
        const float4* xg4 = (const float4*)x + (size_t)gr0 * 32;
        float4* oq4 = (float4*)out_q + (size_t)gr0 * 32;
#pragma unroll
        for (int p = 0; p < 4; ++p) {
            int lin = p * 256 + t;
            int r = lin >> 5, d4 = lin & 31;
            int ix = winL[r];
            float4 cv = cg4[(size_t)ix * 32 + d4];
            float4 xv = xg4[lin];
            float4 o;
            o.x = xv.x + (cv.x - xv.x);
            o.y = xv.y + (cv.y - xv.y);
            o.z = xv.z + (cv.z - xv.z);
            o.w = xv.w + (cv.w - xv.w);
            oq4[lin] = o;
        }
    }
}

extern "C" void kernel_launch(void* const* d_in, const int* in_sizes, int n_in,
                              void* d_out, int out_size, void* d_ws, size_t ws_size,
                              hipStream_t stream) {
    const float* x       = (const float*)d_in[0];
    const float* centers = (const float*)d_in[1];
    // d_in[2] = labels (int64) — unused by the forward computation
    float* out = (float*)d_out;

    _Float16* wh = (_Float16*)d_ws;                 // K*D halves, chunk-major
    _Float16* wl = wh + (size_t)K * D;
    float*    c2 = (float*)(wl + (size_t)K * D);

    pack_kernel<<<(K * 16) / 256, 256, 0, stream>>>(centers, wh, wl, c2);
    dist_kernel<<<BATCH / ROWS_PER_BLOCK, 256, 0, stream>>>(x, centers, wh, wl, c2, out);
}

// Round 4
// 197.699 us; speedup vs baseline: 1.7417x; 1.7417x over previous
//
#include <hip/hip_runtime.h>
#include <math.h>

#define BATCH  32768
#define D      128
#define K      6400
#define KC     64
#define ROWS_PER_BLOCK 64
#define CHUNK_C 128
#define NCHUNK (K / CHUNK_C)   // 50

typedef _Float16 half8 __attribute__((ext_vector_type(8)));
typedef float    floatx4 __attribute__((ext_vector_type(4)));

typedef __attribute__((address_space(3))) unsigned       lds_uint;
typedef __attribute__((address_space(1))) const unsigned glb_uint;

__device__ __forceinline__ void async_lds16(const void* g, void* l) {
    __builtin_amdgcn_global_load_lds((glb_uint*)g, (lds_uint*)l, 16, 0, 0);
}

// ---- pack centers to fp16 (chunk-major for global_load_lds) + c2n = -0.5*||c||^2 ----
// 16B unit n = ch*2048 + u*128 + cw  holds center (ch*128+cw), k in [u*8, u*8+8).
__global__ __launch_bounds__(256) void pack_kernel(const float* __restrict__ centers,
                                                   _Float16* __restrict__ wh,
                                                   float* __restrict__ c2n) {
    int tid = blockIdx.x * 256 + threadIdx.x;   // 0 .. K*16-1
    int ch = tid >> 11;
    int u  = (tid >> 7) & 15;
    int cw = tid & 127;
    int center = ch * CHUNK_C + cw;
    const float* src = centers + (size_t)center * D + u * 8;
    float4 a = *(const float4*)src;
    float4 b = *(const float4*)(src + 4);
    float f[8] = {a.x, a.y, a.z, a.w, b.x, b.y, b.z, b.w};
    half8 h;
#pragma unroll
    for (int j = 0; j < 8; ++j) h[j] = (_Float16)f[j];
    *(half8*)(wh + (size_t)tid * 8) = h;

    // fused c2n: blocks 0..99 each cover 64 centers, 4 threads per center
    if (blockIdx.x < K / KC) {
        int c_local = threadIdx.x >> 2, part = threadIdx.x & 3;
        int c = blockIdx.x * 64 + c_local;
        const float4* p = (const float4*)(centers + (size_t)c * D + part * 32);
        float s = 0.f;
#pragma unroll
        for (int i = 0; i < 8; ++i) {
            float4 v = p[i];
            s = fmaf(v.x, v.x, s); s = fmaf(v.y, v.y, s);
            s = fmaf(v.z, v.z, s); s = fmaf(v.w, v.w, s);
        }
        s += __shfl_xor(s, 1, 64);
        s += __shfl_xor(s, 2, 64);
        if (part == 0) c2n[c] = -0.5f * s;
    }
}

// ---- main fused kernel (R2 geometry, 1-pass fp16 scores) ----
// Block: 256 threads = 4 waves, 64 rows. wave w: rowhalf=w&1, chalf=w>>1.
// Wave tile 32 rows x 64 centers, A fp16 register-resident, B via global_load_lds.
// acc initialized to -c2/2: acc_final = dot - c2/2; argmin dist <=> argmax acc.
// Quad-reduce 4 ct-scores per row-slot, best-2 per (row, n16-stream); merge to
// best-2 per (row, 1600-center group) -> 8 candidates/row; exact fp32 refine.
__global__ __launch_bounds__(256, 2) void dist_kernel(
    const float* __restrict__ x, const float* __restrict__ centers,
    const _Float16* __restrict__ wh, const float* __restrict__ c2n,
    float* __restrict__ out) {
    __shared__ char lds[32768];

    const int t    = threadIdx.x;
    const int w    = t >> 6;
    const int L    = t & 63;
    const int quad = L >> 4;
    const int n16  = L & 15;
    const int rowhalf = w & 1;
    const int chalf   = w >> 1;
    const int gr0  = blockIdx.x * ROWS_PER_BLOCK;

    // ---- preload A fragments (this wave's 32 rows, all 128 k, fp16) ----
    half8 Ah[2][4];
#pragma unroll
    for (int rt = 0; rt < 2; ++rt) {
        int r = gr0 + rowhalf * 32 + rt * 16 + n16;
        const float* xr = x + (size_t)r * D + quad * 8;
#pragma unroll
        for (int ks = 0; ks < 4; ++ks) {
            float4 a = *(const float4*)(xr + ks * 32);
            float4 b = *(const float4*)(xr + ks * 32 + 4);
            float f[8] = {a.x, a.y, a.z, a.w, b.x, b.y, b.z, b.w};
            half8 h;
#pragma unroll
            for (int j = 0; j < 8; ++j) h[j] = (_Float16)f[j];
            Ah[rt][ks] = h;
        }
    }

    // best-2 (max) per slot k = rt*4+reg  (slot = one row, this n16-stream)
    float b1[8], b2[8];
    int   j1_[8], j2_[8];
#pragma unroll
    for (int k = 0; k < 8; ++k) { b1[k] = -3.4e38f; b2[k] = -3.4e38f; j1_[k] = 0; j2_[k] = 0; }

    for (int ch = 0; ch < NCHUNK; ++ch) {
        __syncthreads();   // previous chunk's LDS reads complete
        const char* gh = (const char*)wh + (size_t)ch * 32768;
#pragma unroll
        for (int i = 0; i < 8; ++i) {
            int seg = w + i * 4;                       // wave-uniform
            async_lds16(gh + seg * 1024 + L * 16, lds + seg * 1024);
        }
        const int kbase = ch * CHUNK_C + chalf * 64;
        float c2v[4];
#pragma unroll
        for (int ct = 0; ct < 4; ++ct) c2v[ct] = c2n[kbase + ct * 16 + n16];
        __syncthreads();   // staging complete

        floatx4 acc[2][4];
#pragma unroll
        for (int rt = 0; rt < 2; ++rt)
#pragma unroll
            for (int ct = 0; ct < 4; ++ct)
                acc[rt][ct] = (floatx4){c2v[ct], c2v[ct], c2v[ct], c2v[ct]};

#pragma unroll
        for (int ks = 0; ks < 4; ++ks) {
            const half8* pb = (const half8*)lds + (ks * 4 + quad) * 128 + chalf * 64 + n16;
#pragma unroll
            for (int ct = 0; ct < 4; ++ct) {
                half8 Bf = pb[ct * 16];
                acc[0][ct] = __builtin_amdgcn_mfma_f32_16x16x32_f16(Ah[0][ks], Bf, acc[0][ct], 0, 0, 0);
                acc[1][ct] = __builtin_amdgcn_mfma_f32_16x16x32_f16(Ah[1][ks], Bf, acc[1][ct], 0, 0, 0);
            }
        }

        // quad-reduce over ct (same row!) then best-2 insert per slot.
        // idx ascending in ct; strict > keeps first occurrence.
        int i0 = kbase + n16;
#pragma unroll
        for (int rt = 0; rt < 2; ++rt)
#pragma unroll
            for (int reg = 0; reg < 4; ++reg) {
                float s0 = acc[rt][0][reg], s1 = acc[rt][1][reg];
                float s2 = acc[rt][2][reg], s3 = acc[rt][3][reg];
                bool g01 = s1 > s0, g23 = s3 > s2;
                float m01 = g01 ? s1 : s0;  int x01 = g01 ? i0 + 16 : i0;
                float m23 = g23 ? s3 : s2;  int x23 = g23 ? i0 + 48 : i0 + 32;
                bool gq = m23 > m01;
                float q  = gq ? m23 : m01;  int qi = gq ? x23 : x01;
                int k = rt * 4 + reg;
                bool bet1 = q > b1[k];
                bool bet2 = q > b2[k];
                float nb2 = bet1 ? b1[k] : (bet2 ? q : b2[k]);
                int   nj2 = bet1 ? j1_[k] : (bet2 ? qi : j2_[k]);
                b1[k]  = bet1 ? q : b1[k];
                j1_[k] = bet1 ? qi : j1_[k];
                b2[k]  = nb2;
                j2_[k] = nj2;
            }
    }

    __syncthreads();              // LDS free for reuse
    int* candL = (int*)lds;       // [64 rows][8 candidates]

    // merge sorted best-2 (max) across 8-lane n16 groups -> best-2 per 1600-center group
#pragma unroll
    for (int k = 0; k < 8; ++k) {
        float v1 = b1[k], v2 = b2[k];
        int   p1 = j1_[k], p2 = j2_[k];
#pragma unroll
        for (int m = 1; m < 8; m <<= 1) {
            float o1 = __shfl_xor(v1, m, 64), o2 = __shfl_xor(v2, m, 64);
            int   q1 = __shfl_xor(p1, m, 64), q2 = __shfl_xor(p2, m, 64);
            bool firstMine = (v1 > o1) || (v1 == o1 && p1 < q1);
            float nv1 = firstMine ? v1 : o1;  int np1 = firstMine ? p1 : q1;
            float cb  = firstMine ? o1 : v1;  int cpi = firstMine ? q1 : p1;  // loser of firsts
            float ob  = firstMine ? v2 : o2;  int obi = firstMine ? p2 : q2;  // winner's own 2nd
            bool secOwn = (ob > cb) || (ob == cb && obi < cpi);
            v1 = nv1; p1 = np1;
            v2 = secOwn ? ob : cb;  p2 = secOwn ? obi : cpi;
        }
        if ((n16 & 7) == 0) {
            int rloc = rowhalf * 32 + (k >> 2) * 16 + quad * 4 + (k & 3);
            int g = chalf * 2 + (n16 >> 3);
            candL[rloc * 8 + g * 2 + 0] = p1;
            candL[rloc * 8 + g * 2 + 1] = p2;
        }
    }
    __syncthreads();

    float* out_q   = out;
    float* out_clu = out + (size_t)BATCH * D;
    float* out_md  = out_clu + BATCH;
    float* out_cls = out_md + BATCH;

    // exact fp32 refine: 8 candidates/row, 2 per thread (64 rows x 4 threads)
    {
        int r = t >> 2, p = t & 3;
        int ixa = candL[r * 8 + p * 2 + 0];
        int ixb = candL[r * 8 + p * 2 + 1];
        const float4* xr4 = (const float4*)(x + (size_t)(gr0 + r) * D);
        const float4* ca4 = (const float4*)(centers + (size_t)ixa * D);
        const float4* cb4 = (const float4*)(centers + (size_t)ixb * D);
        float dota = 0.f, dotb = 0.f, x2s = 0.f, c2a = 0.f, c2b = 0.f;
#pragma unroll
        for (int d4 = 0; d4 < 32; ++d4) {
            float4 xv = xr4[d4], av = ca4[d4], bv = cb4[d4];
            dota = fmaf(xv.x, av.x, dota); dota = fmaf(xv.y, av.y, dota);
            dota = fmaf(xv.z, av.z, dota); dota = fmaf(xv.w, av.w, dota);
            dotb = fmaf(xv.x, bv.x, dotb); dotb = fmaf(xv.y, bv.y, dotb);
            dotb = fmaf(xv.z, bv.z, dotb); dotb = fmaf(xv.w, bv.w, dotb);
            x2s = fmaf(xv.x, xv.x, x2s); x2s = fmaf(xv.y, xv.y, x2s);
            x2s = fmaf(xv.z, xv.z, x2s); x2s = fmaf(xv.w, xv.w, x2s);
            c2a = fmaf(av.x, av.x, c2a); c2a = fmaf(av.y, av.y, c2a);
            c2a = fmaf(av.z, av.z, c2a); c2a = fmaf(av.w, av.w, c2a);
            c2b = fmaf(bv.x, bv.x, c2b); c2b = fmaf(bv.y, bv.y, c2b);
            c2b = fmaf(bv.z, bv.z, c2b); c2b = fmaf(bv.w, bv.w, c2b);
        }
        float sqa = x2s + c2a - 2.f * dota;
        float sqb = x2s + c2b - 2.f * dotb;
        bool aw = (sqa < sqb) || (sqa == sqb && ixa < ixb);
        float sq = aw ? sqa : sqb;
        int   ix = aw ? ixa : ixb;
#pragma unroll
        for (int m = 1; m < 4; m <<= 1) {
            float osq = __shfl_xor(sq, m, 64);
            int   oix = __shfl_xor(ix, m, 64);
            if (osq < sq || (osq == sq && oix < ix)) { sq = osq; ix = oix; }
        }
        int* winL = (int*)(lds + 16384);
        if (p == 0) {
            out_md[gr0 + r]  = sqrtf(fmaxf(sq, 0.f));
            out_clu[gr0 + r] = (float)(ix & (KC - 1));
            out_cls[gr0 + r] = (float)(ix >> 6);
            winL[r] = ix;
        }
    }
    __syncthreads();

    // quantized = x + (c - x), coalesced
    {
        const int* winL = (const int*)(lds + 16384);
        const float4* cg4 = (const float4*)centers;
        const float4* xg4 = (const float4*)x + (size_t)gr0 * 32;
        float4* oq4 = (float4*)out_q + (size_t)gr0 * 32;
#pragma unroll
        for (int p = 0; p < 8; ++p) {
            int lin = p * 256 + t;
            int r = lin >> 5, d4 = lin & 31;
            int ix = winL[r];
            float4 cv = cg4[(size_t)ix * 32 + d4];
            float4 xv = xg4[lin];
            float4 o;
            o.x = xv.x + (cv.x - xv.x);
            o.y = xv.y + (cv.y - xv.y);
            o.z = xv.z + (cv.z - xv.z);
            o.w = xv.w + (cv.w - xv.w);
            oq4[lin] = o;
        }
    }
}

extern "C" void kernel_launch(void* const* d_in, const int* in_sizes, int n_in,
                              void* d_out, int out_size, void* d_ws, size_t ws_size,
                              hipStream_t stream) {
    const float* x       = (const float*)d_in[0];
    const float* centers = (const float*)d_in[1];
    // d_in[2] = labels (int64) — unused by the forward computation
    float* out = (float*)d_out;

    _Float16* wh  = (_Float16*)d_ws;                // K*D halves, chunk-major
    float*    c2n = (float*)(wh + (size_t)K * D);   // -0.5*||c||^2

    pack_kernel<<<(K * 16) / 256, 256, 0, stream>>>(centers, wh, c2n);
    dist_kernel<<<BATCH / ROWS_PER_BLOCK, 256, 0, stream>>>(x, centers, wh, c2n, out);
}